// Round 6
// baseline (364.610 us; speedup 1.0000x reference)
//
#include <hip/hip_runtime.h>
#include <math.h>

#define LAMBDA_INIT_F 0.7836057665316245f
#define ONE_MINUS_LI  0.2163942334683755f

typedef unsigned short ushort_t;
typedef unsigned int   uint32;
typedef unsigned long long u64;
typedef __attribute__((ext_vector_type(8))) short short8;
typedef __attribute__((ext_vector_type(4))) float f32x4;

// float -> bf16 (RNE)
__device__ __forceinline__ ushort_t f2bf(float f) {
    union { float f; uint32 u; } x; x.f = f;
    uint32 r = (x.u + 0x7fffu + ((x.u >> 16) & 1u)) >> 16;
    return (ushort_t)r;
}

// async global->LDS, 16B per lane. lds must be wave-uniform base; HW adds lane*16.
__device__ __forceinline__ void gld16(ushort_t* lds, const ushort_t* g) {
    __builtin_amdgcn_global_load_lds(
        (const __attribute__((address_space(1))) uint32*)g,
        (__attribute__((address_space(3))) uint32*)lds,
        16, 0, 0);
}

// ---------------------------------------------------------------------------
__global__ __launch_bounds__(64) void lambda_kernel(
    const float* __restrict__ lq1, const float* __restrict__ lk1,
    const float* __restrict__ lq2, const float* __restrict__ lk2,
    float* __restrict__ lam)
{
    int l = threadIdx.x;
    float p1 = lq1[l] * lk1[l];
    float p2 = lq2[l] * lk2[l];
    for (int off = 32; off; off >>= 1) {
        p1 += __shfl_down(p1, off);
        p2 += __shfl_down(p2, off);
    }
    if (l == 0) lam[0] = expf(p1) - expf(p2) + LAMBDA_INIT_F;
}

// g[j] = irfft(gaussian filter)[tau=j-64], j in [0,129). Parallel k-sum.
__global__ __launch_bounds__(256) void gfilt_kernel(float* __restrict__ g)
{
    __shared__ float red[4];
    const int j = blockIdx.x;            // 0..128
    int tau = j - 64;
    int ta = tau < 0 ? -tau : tau;       // cos is even
    const int tid = threadIdx.x;
    float acc = 0.0f;
    for (int k = tid; k <= 1024; k += 256) {
        float w = (k == 0 || k == 1024) ? 1.0f : 2.0f;
        float r = (float)k * (1.0f / 153.6f);
        float f = expf(-0.5f * r * r);
        int m = (k * ta) & 2047;
        float ang = (float)m * 3.0679615757712823e-3f;
        acc += w * f * cosf(ang);
    }
    for (int off = 32; off; off >>= 1) acc += __shfl_down(acc, off);
    if ((tid & 63) == 0) red[tid >> 6] = acc;
    __syncthreads();
    if (tid == 0)
        g[j] = (red[0] + red[1] + red[2] + red[3]) * (1.0f / 2048.0f);
}

// rotary tables: ct/st[t*32 + i] = cos/sin(t * 10000^(-i/32))
__global__ __launch_bounds__(256) void rottab(float* __restrict__ ct, float* __restrict__ st)
{
    int id = blockIdx.x * 256 + threadIdx.x;
    int t = id >> 5, i = id & 31;
    double inv = exp(-0.28782313662425575 * (double)i);
    double a = (double)t * inv;
    ct[id] = (float)cos(a);
    st[id] = (float)sin(a);
}

// fp32 -> bf16 elementwise (8/thread)
__global__ __launch_bounds__(256) void cvt_bf16(const float* __restrict__ s, ushort_t* __restrict__ d)
{
    int i = (blockIdx.x * 256 + threadIdx.x) * 8;
    float4 a = *(const float4*)(s + i);
    float4 b = *(const float4*)(s + i + 4);
    uint4 pk;
    pk.x = (uint32)f2bf(a.x) | ((uint32)f2bf(a.y) << 16);
    pk.y = (uint32)f2bf(a.z) | ((uint32)f2bf(a.w) << 16);
    pk.z = (uint32)f2bf(b.x) | ((uint32)f2bf(b.y) << 16);
    pk.w = (uint32)f2bf(b.z) | ((uint32)f2bf(b.w) << 16);
    *(uint4*)(d + i) = pk;
}

// Transpose W[k][n] fp32 -> WT[n'][k] bf16. For z<2 (Wq,Wk) permute n within each
// 64-col head2 group: n' = head2*64 + (d&1)*32 + (d>>1)  (de-interleave rotary pairs)
__global__ __launch_bounds__(256) void wtrans(
    const float* __restrict__ Wq, const float* __restrict__ Wk,
    const float* __restrict__ Wv, const float* __restrict__ Wo,
    ushort_t* __restrict__ Tq, ushort_t* __restrict__ Tk,
    ushort_t* __restrict__ Tv, ushort_t* __restrict__ To)
{
    int z = blockIdx.z;
    const float* S = (z == 0) ? Wq : (z == 1) ? Wk : (z == 2) ? Wv : Wo;
    ushort_t* Dt = (z == 0) ? Tq : (z == 1) ? Tk : (z == 2) ? Tv : To;
    bool perm = (z < 2);
    __shared__ float Ls[64 * 65];
    const int tid = threadIdx.x;
    const int n0 = blockIdx.x * 64, k0 = blockIdx.y * 64;
    #pragma unroll
    for (int it = 0; it < 4; ++it) {
        int kk = it * 16 + (tid >> 4);
        int nn = (tid & 15) * 4;
        float4 v = *(const float4*)(S + (size_t)(k0 + kk) * 2048 + n0 + nn);
        Ls[(nn + 0) * 65 + kk] = v.x;
        Ls[(nn + 1) * 65 + kk] = v.y;
        Ls[(nn + 2) * 65 + kk] = v.z;
        Ls[(nn + 3) * 65 + kk] = v.w;
    }
    __syncthreads();
    int nl = tid >> 2, kc = (tid & 3) * 16;
    int ng = n0 + nl;
    int nd = perm ? ((ng & ~63) | ((ng & 1) << 5) | ((ng & 63) >> 1)) : ng;
    uint4 p0, p1;
    const float* row = Ls + nl * 65 + kc;
    p0.x = (uint32)f2bf(row[0])  | ((uint32)f2bf(row[1])  << 16);
    p0.y = (uint32)f2bf(row[2])  | ((uint32)f2bf(row[3])  << 16);
    p0.z = (uint32)f2bf(row[4])  | ((uint32)f2bf(row[5])  << 16);
    p0.w = (uint32)f2bf(row[6])  | ((uint32)f2bf(row[7])  << 16);
    p1.x = (uint32)f2bf(row[8])  | ((uint32)f2bf(row[9])  << 16);
    p1.y = (uint32)f2bf(row[10]) | ((uint32)f2bf(row[11]) << 16);
    p1.z = (uint32)f2bf(row[12]) | ((uint32)f2bf(row[13]) << 16);
    p1.w = (uint32)f2bf(row[14]) | ((uint32)f2bf(row[15]) << 16);
    *(uint4*)(Dt + (size_t)nd * 2048 + k0 + kc) = p0;
    *(uint4*)(Dt + (size_t)nd * 2048 + k0 + kc + 8) = p1;
}

// ---------------------------------------------------------------------------
// Fused QKV GEMM, 256x256 tile, 8-wave, 8-phase counted-vmcnt pipeline with
// CROSS-PHASE READ-AHEAD (audited r5 schedule, resubmitted after infra flake):
//   P4(t): stage A[p]h1,B[p]h0(t+2); VM6; SB; rd{afc,bf0}(t+1); mfma<1,1>; SB
//   P1:    rd bf1; stage B[q]h1(t+1); SB; mfma<0,0>(afc,bf0); SB
//   P2:    rd afn; stage A[p]h0(t+2); SB; mfma<0,1>(afc,bf1); SB
//   P3:    (no reads);                    mfma<1,0>(afn,bf0); SB
// Every rd target is VM6-drained + SB-published before issue; every stage
// target's old-content readers are lgkm-forced complete >=1 barrier earlier.
#define SB()     __builtin_amdgcn_s_barrier()
#define SCHED0() __builtin_amdgcn_sched_barrier(0)
#define VM6()    asm volatile("s_waitcnt vmcnt(6)" ::: "memory")

__device__ __forceinline__ void rdA(short8 af[8], const ushort_t* Ah, int rbase, int quad)
{
    #pragma unroll
    for (int m = 0; m < 4; ++m) {
        int r = rbase + m * 16;
        #pragma unroll
        for (int ks = 0; ks < 2; ++ks)
            af[m * 2 + ks] = *(const short8*)(Ah + r * 64 + ((ks * 4 + quad) ^ (r & 7)) * 8);
    }
}
__device__ __forceinline__ void rdB(short8 bf[4], const ushort_t* Bh, int rbase, int quad)
{
    #pragma unroll
    for (int n = 0; n < 2; ++n) {
        int r = rbase + n * 32;
        #pragma unroll
        for (int ks = 0; ks < 2; ++ks)
            bf[n * 2 + ks] = *(const short8*)(Bh + r * 64 + ((ks * 4 + quad) ^ (r & 7)) * 8);
    }
}
template<int QA, int QB>
__device__ __forceinline__ void mfma16(const short8 af[8], const short8 bf[4], f32x4 acc[8][4])
{
    __builtin_amdgcn_s_setprio(1);
    #pragma unroll
    for (int m = 0; m < 4; ++m)
        #pragma unroll
        for (int n = 0; n < 2; ++n)
            #pragma unroll
            for (int ks = 0; ks < 2; ++ks)
                acc[QA * 4 + m][QB * 2 + n] = __builtin_amdgcn_mfma_f32_16x16x32_bf16(
                    af[m * 2 + ks], bf[n * 2 + ks], acc[QA * 4 + m][QB * 2 + n], 0, 0, 0);
    __builtin_amdgcn_s_setprio(0);
}

__global__ __launch_bounds__(512, 2) void gemm_qkv(
    const ushort_t* __restrict__ A, const ushort_t* __restrict__ WT,
    ushort_t* __restrict__ q1, ushort_t* __restrict__ q2,
    ushort_t* __restrict__ k1, ushort_t* __restrict__ k2,
    ushort_t* __restrict__ v1T, ushort_t* __restrict__ v2T,
    const float* __restrict__ ctab, const float* __restrict__ stab)
{
    __shared__ ushort_t sA0h0[8192], sA0h1[8192], sA1h0[8192], sA1h1[8192];
    __shared__ ushort_t sB0h0[8192], sB0h1[8192], sB1h0[8192], sB1h1[8192];
    const int tid = threadIdx.x;
    const int w = tid >> 6, lane = tid & 63;
    const int quad = lane >> 4, l15 = lane & 15;
    const int wr = w >> 2, wc = w & 3;    // 2 (M) x 4 (N) wave grid
    const int rb = blockIdx.y * 256, cbg = blockIdx.x * 256;
    const int rA = wr * 64 + l15;                         // A frag row base
    const int rB = (wc >> 1) * 64 + (wc & 1) * 16 + l15;  // B frag row base
    const int cib = w * 128;                              // per-wave chunk base

    auto stA = [&](ushort_t* buf, int ha, int tau) {
        #pragma unroll
        for (int u = 0; u < 2; ++u) {
            int ci = cib + u * 64 + lane;
            int row = ci >> 3, cc = (ci & 7) ^ (row & 7);
            gld16(buf + (cib + u * 64) * 8,
                  A + (size_t)(rb + ha * 128 + row) * 2048 + tau * 64 + cc * 8);
        }
    };
    auto stB = [&](ushort_t* buf, int hb, int tau) {
        #pragma unroll
        for (int u = 0; u < 2; ++u) {
            int ci = cib + u * 64 + lane;
            int row = ci >> 3, cc = (ci & 7) ^ (row & 7);
            gld16(buf + (cib + u * 64) * 8,
                  WT + (size_t)(cbg + hb * 128 + row) * 2048 + tau * 64 + cc * 8);
        }
    };

    // prologue: tile 0 fully + tile 1 {A h0,h1, B h0}; queue = 7 half-tiles
    stA(sA0h0, 0, 0); stA(sA0h1, 1, 0); stB(sB0h0, 0, 0); stB(sB0h1, 1, 0);
    stA(sA1h0, 0, 1); stA(sA1h1, 1, 1); stB(sB1h0, 0, 1);

    f32x4 acc[8][4];
    #pragma unroll
    for (int i = 0; i < 8; ++i)
        #pragma unroll
        for (int j = 0; j < 4; ++j) acc[i][j] = (f32x4)0.0f;
    short8 afc[8], afn[8], bf0[4], bf1[4];

    VM6();                 // drain tile-0 halves (leave 3 in flight)
    SB();                  // publish across waves
    rdA(afc, sA0h0, rA, quad); rdB(bf0, sB0h0, rB, quad);   // tile-0 lead frags
    SCHED0();

    for (int it = 0; it < 16; ++it) {
        const int t = it * 2;
        const int t1 = t + 1;
        const int t2 = (t + 2 < 32) ? t + 2 : 31;
        const int t3 = (t + 3 < 32) ? t + 3 : 31;
        // ================= tile t (parity 0) =================
        rdB(bf1, sB0h1, rB, quad); SCHED0();                    // P1
        stB(sB1h1, 1, t1);
        SB(); mfma16<0, 0>(afc, bf0, acc); SB();
        rdA(afn, sA0h1, rA, quad); SCHED0();                    // P2
        stA(sA0h0, 0, t2);
        SB(); mfma16<0, 1>(afc, bf1, acc); SB();
        mfma16<1, 0>(afn, bf0, acc); SB();                      // P3
        stA(sA0h1, 1, t2); stB(sB0h0, 0, t2);                   // P4
        VM6();
        SB();
        rdA(afc, sA1h0, rA, quad); rdB(bf0, sB1h0, rB, quad);   // read-ahead t+1
        SCHED0();
        mfma16<1, 1>(afn, bf1, acc); SB();
        // ================= tile t+1 (parity 1) =================
        rdB(bf1, sB1h1, rB, quad); SCHED0();                    // P1
        stB(sB0h1, 1, t2);
        SB(); mfma16<0, 0>(afc, bf0, acc); SB();
        rdA(afn, sA1h1, rA, quad); SCHED0();                    // P2
        stA(sA1h0, 0, t3);
        SB(); mfma16<0, 1>(afc, bf1, acc); SB();
        mfma16<1, 0>(afn, bf0, acc); SB();                      // P3
        stA(sA1h1, 1, t3); stB(sB1h0, 0, t3);                   // P4
        VM6();
        SB();
        rdA(afc, sA0h0, rA, quad); rdB(bf0, sB0h0, rB, quad);   // read-ahead t+2
        SCHED0();
        mfma16<1, 1>(afn, bf1, acc); SB();
    }

    // per-wave output cols: col(nj) = (nj>>1)*128 + (wc>>1)*64 + (wc&1)*16 + (nj&1)*32 + l15
    // per-wave output rows: row(mi) = (mi>>2)*128 + wr*64 + (mi&3)*16 + quad*4 + r
    const int region = cbg >> 11;        // 0=Q, 1=K, 2=V
    const int nloc = cbg & 2047;
    if (region < 2) {
        ushort_t* b1 = region ? k1 : q1;
        ushort_t* b2 = region ? k2 : q2;
        const int i = (wc & 1) * 16 + l15;           // rotary index in [0,32)
        #pragma unroll
        for (int qb = 0; qb < 2; ++qb) {
            int head2 = (nloc >> 6) + qb * 2 + (wc >> 1);
            ushort_t* dst = ((head2 & 1) ? b2 : b1) + (size_t)(head2 >> 1) * 2048 * 64;
            #pragma unroll
            for (int mi = 0; mi < 8; ++mi)
                #pragma unroll
                for (int r = 0; r < 4; ++r) {
                    int t = rb + (mi >> 2) * 128 + wr * 64 + (mi & 3) * 16 + quad * 4 + r;
                    float c = ctab[t * 32 + i], s = stab[t * 32 + i];
                    float x1 = acc[mi][qb * 2 + 0][r], x2 = acc[mi][qb * 2 + 1][r];
                    dst[(size_t)t * 64 + i]      = f2bf(x1 * c - x2 * s);
                    dst[(size_t)t * 64 + 32 + i] = f2bf(x1 * s + x2 * c);
                }
        }
    } else {
        #pragma unroll
        for (int mi = 0; mi < 8; ++mi)
            #pragma unroll
            for (int nj = 0; nj < 4; ++nj) {
                int cg = nloc + (nj >> 1) * 128 + (wc >> 1) * 64 + (wc & 1) * 16
                       + (nj & 1) * 32 + l15;
                int hh = cg >> 7, pr = (cg >> 6) & 1, d = cg & 63;
                int tb = rb + (mi >> 2) * 128 + wr * 64 + (mi & 3) * 16 + quad * 4;
                ushort_t* dst = (pr ? v2T : v1T) + ((size_t)(hh * 64 + d)) * 2048 + tb;
                u64 pk = (u64)f2bf(acc[mi][nj][0])
                       | ((u64)f2bf(acc[mi][nj][1]) << 16)
                       | ((u64)f2bf(acc[mi][nj][2]) << 32)
                       | ((u64)f2bf(acc[mi][nj][3]) << 48);
                *(u64*)dst = pk;
            }
    }
}

// ---------------------------------------------------------------------------
// Pipelined merged attention, 8-wave blocks: waves 0-3 compute attn1, waves
// 4-7 compute attn2 for the same (h, qt). Balanced qt pairing: co-resident
// blocks (b, b+256) get qt summing to 31 -> every CU executes 33 tile-steps.
#define PSTRIDE 88

__device__ __forceinline__ void attn_step(
    const ushort_t* __restrict__ Kb, const ushort_t* __restrict__ V1b,
    const ushort_t* __restrict__ V2b, ushort_t* __restrict__ pw,
    const short8* qb, f32x4* O, float& m_i, float& l_i,
    int quad, int l15, int row_l, bool diag)
{
    f32x4 s[4];
    #pragma unroll
    for (int j = 0; j < 4; ++j) s[j] = (f32x4)0.0f;
    #pragma unroll
    for (int ks = 0; ks < 2; ++ks)
        #pragma unroll
        for (int j = 0; j < 4; ++j) {
            int r = j * 16 + l15;
            short8 kf = *(const short8*)(Kb + r * 64 + ((ks * 4 + quad) ^ (r & 7)) * 8);
            s[j] = __builtin_amdgcn_mfma_f32_16x16x32_bf16(kf, qb[ks], s[j], 0, 0, 0);
        }
    float mx = -1e30f;
    #pragma unroll
    for (int j = 0; j < 4; ++j)
        #pragma unroll
        for (int r = 0; r < 4; ++r) {
            float v = s[j][r] * 0.125f;
            if (diag) {
                int kp = j * 16 + quad * 4 + r;
                v = (kp <= row_l) ? v : -1e30f;
            }
            s[j][r] = v;
            mx = fmaxf(mx, v);
        }
    mx = fmaxf(mx, __shfl_xor(mx, 16));
    mx = fmaxf(mx, __shfl_xor(mx, 32));
    float newm = fmaxf(m_i, mx);
    float alpha = __expf(m_i - newm);
    float sum = 0.0f;
    #pragma unroll
    for (int j = 0; j < 4; ++j) {
        float p0 = __expf(s[j][0] - newm);
        float p1 = __expf(s[j][1] - newm);
        float p2 = __expf(s[j][2] - newm);
        float p3 = __expf(s[j][3] - newm);
        sum += (p0 + p1) + (p2 + p3);
        u64 pk = (u64)f2bf(p0) | ((u64)f2bf(p1) << 16)
               | ((u64)f2bf(p2) << 32) | ((u64)f2bf(p3) << 48);
        *(u64*)(pw + l15 * PSTRIDE + j * 16 + quad * 4) = pk;
    }
    sum += __shfl_xor(sum, 16);
    sum += __shfl_xor(sum, 32);
    l_i = l_i * alpha + sum;
    m_i = newm;
    float av0 = __shfl(alpha, quad * 4 + 0);
    float av1 = __shfl(alpha, quad * 4 + 1);
    float av2 = __shfl(alpha, quad * 4 + 2);
    float av3 = __shfl(alpha, quad * 4 + 3);
    #pragma unroll
    for (int nt = 0; nt < 8; ++nt) {
        O[nt][0] *= av0; O[nt][1] *= av1; O[nt][2] *= av2; O[nt][3] *= av3;
    }
    #pragma unroll
    for (int ks = 0; ks < 2; ++ks) {
        short8 pf = *(const short8*)(pw + l15 * PSTRIDE + ks * 32 + quad * 8);
        #pragma unroll
        for (int nt = 0; nt < 8; ++nt) {
            const ushort_t* Vs = (nt < 4) ? V1b : V2b;
            int d = (nt & 3) * 16 + l15;
            short8 vf = *(const short8*)(Vs + d * 64 + ((ks * 4 + quad) ^ (d & 7)) * 8);
            O[nt] = __builtin_amdgcn_mfma_f32_16x16x32_bf16(pf, vf, O[nt], 0, 0, 0);
        }
    }
}

__global__ __launch_bounds__(512, 4) void attn_pipe(
    const ushort_t* __restrict__ q1, const ushort_t* __restrict__ k1,
    const ushort_t* __restrict__ q2, const ushort_t* __restrict__ k2,
    const ushort_t* __restrict__ v1T, const ushort_t* __restrict__ v2T,
    float* __restrict__ X, const float* __restrict__ lam_ptr)
{
    __shared__ ushort_t Tt[4][4096];    // K1,K2,V1,V2 current tile (swizzled chunks)
    __shared__ ushort_t Ps[8][16 * PSTRIDE];

    const int tid = threadIdx.x;
    const int w = tid >> 6, lane = tid & 63;
    const int quad = lane >> 4, l15 = lane & 15;
    const int pair = w >> 2, wl = w & 3;  // pair: 0=attn1 waves, 1=attn2 waves
    const int b = blockIdx.x;
    const int h = b & 15;                // head -> fixed XCD (b%8): L2 locality
    const int x16 = (b & 255) >> 4;
    const int qt = (b < 256) ? (31 - x16) : x16;  // (b,b+256) work sums to 33
    const float lam = lam_ptr[0];
    const int row_l = wl * 16 + l15;

    const ushort_t* k1h = k1 + (size_t)h * 2048 * 64;
    const ushort_t* k2h = k2 + (size_t)h * 2048 * 64;
    const ushort_t* v1h = v1T + (size_t)h * 64 * 2048;
    const ushort_t* v2h = v2T + (size_t)h * 64 * 2048;

    // Q fragments direct from global (pair selects q1/q2)
    short8 qb[2];
    {
        const ushort_t* qp = (pair ? q2 : q1)
            + ((size_t)h * 2048 + qt * 64 + wl * 16 + l15) * 64 + quad * 8;
        qb[0] = *(const short8*)(qp);
        qb[1] = *(const short8*)(qp + 32);
    }

    const int ci = tid;
    const int srow = ci >> 3, scc = (ci & 7) ^ (srow & 7);
    const int koff = srow * 64 + scc * 8;     // K tile: row stride 64
    const int voff = srow * 2048 + scc * 8;   // V^T: row stride 2048

    short8 sK1, sK2, sV1, sV2;

    sK1 = *(const short8*)(k1h + koff);
    sK2 = *(const short8*)(k2h + koff);
    sV1 = *(const short8*)(v1h + voff);
    sV2 = *(const short8*)(v2h + voff);
    *(short8*)(&Tt[0][ci * 8]) = sK1;
    *(short8*)(&Tt[1][ci * 8]) = sK2;
    *(short8*)(&Tt[2][ci * 8]) = sV1;
    *(short8*)(&Tt[3][ci * 8]) = sV2;
    __syncthreads();

    f32x4 O[8];
    #pragma unroll
    for (int i = 0; i < 8; ++i) O[i] = (f32x4)0.0f;
    float m_i = -1e30f, l_i = 0.0f;

    const ushort_t* Kb = Tt[pair];

    for (int kt = 0; kt <= qt; ++kt) {
        if (kt < qt) {
            int kb = (kt + 1) * 4096, vb = (kt + 1) * 64;
            sK1 = *(const short8*)(k1h + kb + koff);
            sK2 = *(const short8*)(k2h + kb + koff);
            sV1 = *(const short8*)(v1h + vb + voff);
            sV2 = *(const short8*)(v2h + vb + voff);
        }
        attn_step(Kb, Tt[2], Tt[3], &Ps[w][0], qb, O, m_i, l_i,
                  quad, l15, row_l, kt == qt);
        __syncthreads();
        if (kt < qt) {
            *(short8*)(&Tt[0][ci * 8]) = sK1;
            *(short8*)(&Tt[1][ci * 8]) = sK2;
            *(short8*)(&Tt[2][ci * 8]) = sV1;
            *(short8*)(&Tt[3][ci * 8]) = sV2;
            __syncthreads();
        }
    }

    // epilogue: X = O1/l1 - lam * O2/l2; combine across pair halves via LDS.
    float sc = pair ? lam : 1.0f;
    float rr0 = sc / __shfl(l_i, quad * 4 + 0);
    float rr1 = sc / __shfl(l_i, quad * 4 + 1);
    float rr2 = sc / __shfl(l_i, quad * 4 + 2);
    float rr3 = sc / __shfl(l_i, quad * 4 + 3);

    float* LX = (float*)&Tt[0][0];       // 64 rows x 128 cols fp32 = 32 KB
    const int rbase = wl * 16 + quad * 4;
    if (pair) {
        #pragma unroll
        for (int nt = 0; nt < 8; ++nt) {
            int cb = nt * 16 + l15;
            LX[(rbase + 0) * 128 + cb] = O[nt][0] * rr0;
            LX[(rbase + 1) * 128 + cb] = O[nt][1] * rr1;
            LX[(rbase + 2) * 128 + cb] = O[nt][2] * rr2;
            LX[(rbase + 3) * 128 + cb] = O[nt][3] * rr3;
        }
    }
    __syncthreads();
    if (!pair) {
        int tb = qt * 64 + rbase;
        #pragma unroll
        for (int nt = 0; nt < 8; ++nt) {
            int cb = nt * 16 + l15;
            int col = h * 128 + cb;
            X[(size_t)(tb + 0) * 2048 + col] = O[nt][0] * rr0 - LX[(rbase + 0) * 128 + cb];
            X[(size_t)(tb + 1) * 2048 + col] = O[nt][1] * rr1 - LX[(rbase + 1) * 128 + cb];
            X[(size_t)(tb + 2) * 2048 + col] = O[nt][2] * rr2 - LX[(rbase + 2) * 128 + cb];
            X[(size_t)(tb + 3) * 2048 + col] = O[nt][3] * rr3 - LX[(rbase + 3) * 128 + cb];
        }
    }
}

// ---------------------------------------------------------------------------
// LDS-tiled truncated circular conv along t (129 taps); g[j]=g(tau=j-64)
__global__ __launch_bounds__(256) void conv_t(
    const float* __restrict__ X, const float* __restrict__ g, float* __restrict__ Y)
{
    __shared__ float Xs[192 * 64];
    __shared__ float gs[129];
    const int tid = threadIdx.x;
    const int c0 = blockIdx.x * 64, t0 = blockIdx.y * 64;
    const int c = tid & 63, tg = tid >> 6;
    for (int j = tg; j < 192; j += 4)
        Xs[j * 64 + c] = X[(size_t)((t0 - 64 + j) & 2047) * 2048 + c0 + c];
    if (tid < 129) gs[tid] = g[tid];
    __syncthreads();
    float accv[16];
    #pragma unroll
    for (int i = 0; i < 16; ++i) accv[i] = 0.0f;
    const int tl0 = tg * 16;
    for (int tap = 0; tap < 129; ++tap) {
        float gv = gs[tap];
        int base = (tl0 + 128 - tap) * 64 + c;
        #pragma unroll
        for (int i = 0; i < 16; ++i) accv[i] += gv * Xs[base + i * 64];
    }
    #pragma unroll
    for (int i = 0; i < 16; ++i)
        Y[(size_t)(t0 + tl0 + i) * 2048 + c0 + c] = accv[i];
}

// RMSNorm over 128 per (t,h); writes bf16 for the final GEMM
__global__ __launch_bounds__(64) void rms_bf(
    const float* __restrict__ Y, const float* __restrict__ wgt, ushort_t* __restrict__ yb)
{
    int grp = blockIdx.x;
    int t = grp >> 4, hh = grp & 15, l = threadIdx.x;
    size_t base = (size_t)t * 2048 + hh * 128;
    float a = Y[base + l];
    float b = Y[base + 64 + l];
    float ss = a * a + b * b;
    for (int off = 32; off; off >>= 1) ss += __shfl_down(ss, off);
    ss = __shfl(ss, 0);
    float r = rsqrtf(ss * (1.0f / 128.0f) + 1e-5f) * ONE_MINUS_LI;
    yb[base + l]      = f2bf(a * r * wgt[l]);
    yb[base + 64 + l] = f2bf(b * r * wgt[64 + l]);
}

// ---------------------------------------------------------------------------
// Final GEMM: 64x128 tile (grid 512 -> 2 blocks/CU). out = ybf * WoutT^T, fp32 out.
__global__ __launch_bounds__(256) void gemm_out(
    const ushort_t* __restrict__ A, const ushort_t* __restrict__ BT,
    float* __restrict__ C)
{
    __shared__ ushort_t As[4096];
    __shared__ ushort_t Bs[8192];
    const int tid = threadIdx.x;
    const int w = tid >> 6, lane = tid & 63;
    const int quad = lane >> 4, l15 = lane & 15;
    const int wr = w >> 1, wc = w & 1;
    const int rb = blockIdx.y * 64, cb = blockIdx.x * 128;

    f32x4 acc[2][4];
    #pragma unroll
    for (int i = 0; i < 2; ++i)
        #pragma unroll
        for (int j = 0; j < 4; ++j) acc[i][j] = (f32x4)0.0f;

    for (int k0 = 0; k0 < 2048; k0 += 64) {
        #pragma unroll
        for (int u = 0; u < 2; ++u) {
            int off = (w * 2 + u) * 512;
            int Lc = (off >> 3) + lane;
            int row = Lc >> 3, cc = (Lc & 7) ^ (row & 7);
            gld16(As + off, A + (size_t)(rb + row) * 2048 + k0 + cc * 8);
        }
        #pragma unroll
        for (int u = 0; u < 4; ++u) {
            int off = (w * 4 + u) * 512;
            int Lc = (off >> 3) + lane;
            int row = Lc >> 3, cc = (Lc & 7) ^ (row & 7);
            gld16(Bs + off, BT + (size_t)(cb + row) * 2048 + k0 + cc * 8);
        }
        __syncthreads();
        #pragma unroll
        for (int ks = 0; ks < 2; ++ks) {
            short8 af[2], bfr[4];
            #pragma unroll
            for (int mi = 0; mi < 2; ++mi) {
                int r = wr * 32 + mi * 16 + l15;
                af[mi] = *(const short8*)(As + r * 64 + ((ks * 4 + quad) ^ (r & 7)) * 8);
            }
            #pragma unroll
            for (int nj = 0; nj < 4; ++nj) {
                int r = wc * 64 + nj * 16 + l15;
                bfr[nj] = *(const short8*)(Bs + r * 64 + ((ks * 4 + quad) ^ (r & 7)) * 8);
            }
            #pragma unroll
            for (int mi = 0; mi < 2; ++mi)
                #pragma unroll
                for (int nj = 0; nj < 4; ++nj)
                    acc[mi][nj] = __builtin_amdgcn_mfma_f32_16x16x32_bf16(
                        af[mi], bfr[nj], acc[mi][nj], 0, 0, 0);
        }
        __syncthreads();
    }

    #pragma unroll
    for (int mi = 0; mi < 2; ++mi)
        #pragma unroll
        for (int nj = 0; nj < 4; ++nj) {
            int cg = cb + wc * 64 + nj * 16 + l15;
            #pragma unroll
            for (int r = 0; r < 4; ++r) {
                int t = rb + wr * 32 + mi * 16 + quad * 4 + r;
                C[(size_t)t * 2048 + cg] = acc[mi][nj][r];
            }
        }
}

// ---------------------------------------------------------------------------
extern "C" void kernel_launch(void* const* d_in, const int* in_sizes, int n_in,
                              void* d_out, int out_size, void* d_ws, size_t ws_size,
                              hipStream_t stream)
{
    const float* query = (const float*)d_in[0];
    const float* Wq    = (const float*)d_in[1];
    const float* Wk    = (const float*)d_in[2];
    const float* Wv    = (const float*)d_in[3];
    const float* Wout  = (const float*)d_in[4];
    const float* lq1   = (const float*)d_in[5];
    const float* lk1   = (const float*)d_in[6];
    const float* lq2   = (const float*)d_in[7];
    const float* lk2   = (const float*)d_in[8];
    const float* rmsw  = (const float*)d_in[9];
    float* out = (float*)d_out;

    const size_t MB = 1ull << 20;
    char* W = (char*)d_ws;
    ushort_t* WqT   = (ushort_t*)(W + 0 * MB);   // WqT/WkT/WvT contiguous: 24MB block
    ushort_t* WkT   = (ushort_t*)(W + 8 * MB);
    ushort_t* WvT   = (ushort_t*)(W + 16 * MB);
    ushort_t* WoutT = (ushort_t*)(W + 24 * MB);
    ushort_t* qb    = (ushort_t*)(W + 32 * MB);
    ushort_t* q1    = (ushort_t*)(W + 40 * MB);
    ushort_t* q2    = (ushort_t*)(W + 44 * MB);
    ushort_t* k1    = (ushort_t*)(W + 48 * MB);
    ushort_t* k2    = (ushort_t*)(W + 52 * MB);
    ushort_t* v1T   = (ushort_t*)(W + 56 * MB);
    ushort_t* v2T   = (ushort_t*)(W + 60 * MB);
    float*    X     = (float*)   (W + 64 * MB);
    float*    Y     = (float*)   (W + 32 * MB);  // aliases qb/q1/q2 (dead by conv time)
    ushort_t* ybf   = (ushort_t*)(W + 48 * MB);  // aliases k1/k2 (dead by rms time)
    float*    ctab  = (float*)   (W + 80 * MB);
    float*    stab  = (float*)   (W + 80 * MB + 256 * 1024);
    float*    gbuf  = (float*)   (W + 80 * MB + 512 * 1024);
    float*    lam   = (float*)   (W + 80 * MB + 520 * 1024);

    lambda_kernel<<<1, 64, 0, stream>>>(lq1, lk1, lq2, lk2, lam);
    gfilt_kernel<<<129, 256, 0, stream>>>(gbuf);
    rottab<<<256, 256, 0, stream>>>(ctab, stab);
    cvt_bf16<<<2048, 256, 0, stream>>>(query, qb);
    wtrans<<<dim3(32, 32, 4), 256, 0, stream>>>(Wq, Wk, Wv, Wout, WqT, WkT, WvT, WoutT);

    gemm_qkv<<<dim3(24, 8), 512, 0, stream>>>(qb, WqT, q1, q2, k1, k2, v1T, v2T, ctab, stab);

    attn_pipe<<<512, 512, 0, stream>>>(q1, k1, q2, k2, v1T, v2T, X, lam);

    conv_t<<<dim3(32, 32), 256, 0, stream>>>(X, gbuf, Y);
    rms_bf<<<32768, 64, 0, stream>>>(Y, rmsw, ybf);

    gemm_out<<<dim3(16, 32), 256, 0, stream>>>(ybf, WoutT, out);
}

// Round 7
// 319.241 us; speedup vs baseline: 1.1421x; 1.1421x over previous
//
#include <hip/hip_runtime.h>
#include <math.h>

#define LAMBDA_INIT_F 0.7836057665316245f
#define ONE_MINUS_LI  0.2163942334683755f

typedef unsigned short ushort_t;
typedef unsigned int   uint32;
typedef unsigned long long u64;
typedef __attribute__((ext_vector_type(8))) short short8;
typedef __attribute__((ext_vector_type(4))) float f32x4;

// float -> bf16 (RNE)
__device__ __forceinline__ ushort_t f2bf(float f) {
    union { float f; uint32 u; } x; x.f = f;
    uint32 r = (x.u + 0x7fffu + ((x.u >> 16) & 1u)) >> 16;
    return (ushort_t)r;
}

// async global->LDS, 16B per lane. lds must be wave-uniform base; HW adds lane*16.
__device__ __forceinline__ void gld16(ushort_t* lds, const ushort_t* g) {
    __builtin_amdgcn_global_load_lds(
        (const __attribute__((address_space(1))) uint32*)g,
        (__attribute__((address_space(3))) uint32*)lds,
        16, 0, 0);
}

// ---------------------------------------------------------------------------
__global__ __launch_bounds__(64) void lambda_kernel(
    const float* __restrict__ lq1, const float* __restrict__ lk1,
    const float* __restrict__ lq2, const float* __restrict__ lk2,
    float* __restrict__ lam)
{
    int l = threadIdx.x;
    float p1 = lq1[l] * lk1[l];
    float p2 = lq2[l] * lk2[l];
    for (int off = 32; off; off >>= 1) {
        p1 += __shfl_down(p1, off);
        p2 += __shfl_down(p2, off);
    }
    if (l == 0) lam[0] = expf(p1) - expf(p2) + LAMBDA_INIT_F;
}

// g[j] = irfft(gaussian filter)[tau=j-64], j in [0,129). Parallel k-sum.
__global__ __launch_bounds__(256) void gfilt_kernel(float* __restrict__ g)
{
    __shared__ float red[4];
    const int j = blockIdx.x;            // 0..128
    int tau = j - 64;
    int ta = tau < 0 ? -tau : tau;       // cos is even
    const int tid = threadIdx.x;
    float acc = 0.0f;
    for (int k = tid; k <= 1024; k += 256) {
        float w = (k == 0 || k == 1024) ? 1.0f : 2.0f;
        float r = (float)k * (1.0f / 153.6f);
        float f = expf(-0.5f * r * r);
        int m = (k * ta) & 2047;
        float ang = (float)m * 3.0679615757712823e-3f;
        acc += w * f * cosf(ang);
    }
    for (int off = 32; off; off >>= 1) acc += __shfl_down(acc, off);
    if ((tid & 63) == 0) red[tid >> 6] = acc;
    __syncthreads();
    if (tid == 0)
        g[j] = (red[0] + red[1] + red[2] + red[3]) * (1.0f / 2048.0f);
}

// rotary tables: ct/st[t*32 + i] = cos/sin(t * 10000^(-i/32))
__global__ __launch_bounds__(256) void rottab(float* __restrict__ ct, float* __restrict__ st)
{
    int id = blockIdx.x * 256 + threadIdx.x;
    int t = id >> 5, i = id & 31;
    double inv = exp(-0.28782313662425575 * (double)i);
    double a = (double)t * inv;
    ct[id] = (float)cos(a);
    st[id] = (float)sin(a);
}

// fp32 -> bf16 elementwise (8/thread)
__global__ __launch_bounds__(256) void cvt_bf16(const float* __restrict__ s, ushort_t* __restrict__ d)
{
    int i = (blockIdx.x * 256 + threadIdx.x) * 8;
    float4 a = *(const float4*)(s + i);
    float4 b = *(const float4*)(s + i + 4);
    uint4 pk;
    pk.x = (uint32)f2bf(a.x) | ((uint32)f2bf(a.y) << 16);
    pk.y = (uint32)f2bf(a.z) | ((uint32)f2bf(a.w) << 16);
    pk.z = (uint32)f2bf(b.x) | ((uint32)f2bf(b.y) << 16);
    pk.w = (uint32)f2bf(b.z) | ((uint32)f2bf(b.w) << 16);
    *(uint4*)(d + i) = pk;
}

// Transpose W[k][n] fp32 -> WT[n'][k] bf16. For z<2 (Wq,Wk) permute n within each
// 64-col head2 group: n' = head2*64 + (d&1)*32 + (d>>1)  (de-interleave rotary pairs)
__global__ __launch_bounds__(256) void wtrans(
    const float* __restrict__ Wq, const float* __restrict__ Wk,
    const float* __restrict__ Wv, const float* __restrict__ Wo,
    ushort_t* __restrict__ Tq, ushort_t* __restrict__ Tk,
    ushort_t* __restrict__ Tv, ushort_t* __restrict__ To)
{
    int z = blockIdx.z;
    const float* S = (z == 0) ? Wq : (z == 1) ? Wk : (z == 2) ? Wv : Wo;
    ushort_t* Dt = (z == 0) ? Tq : (z == 1) ? Tk : (z == 2) ? Tv : To;
    bool perm = (z < 2);
    __shared__ float Ls[64 * 65];
    const int tid = threadIdx.x;
    const int n0 = blockIdx.x * 64, k0 = blockIdx.y * 64;
    #pragma unroll
    for (int it = 0; it < 4; ++it) {
        int kk = it * 16 + (tid >> 4);
        int nn = (tid & 15) * 4;
        float4 v = *(const float4*)(S + (size_t)(k0 + kk) * 2048 + n0 + nn);
        Ls[(nn + 0) * 65 + kk] = v.x;
        Ls[(nn + 1) * 65 + kk] = v.y;
        Ls[(nn + 2) * 65 + kk] = v.z;
        Ls[(nn + 3) * 65 + kk] = v.w;
    }
    __syncthreads();
    int nl = tid >> 2, kc = (tid & 3) * 16;
    int ng = n0 + nl;
    int nd = perm ? ((ng & ~63) | ((ng & 1) << 5) | ((ng & 63) >> 1)) : ng;
    uint4 p0, p1;
    const float* row = Ls + nl * 65 + kc;
    p0.x = (uint32)f2bf(row[0])  | ((uint32)f2bf(row[1])  << 16);
    p0.y = (uint32)f2bf(row[2])  | ((uint32)f2bf(row[3])  << 16);
    p0.z = (uint32)f2bf(row[4])  | ((uint32)f2bf(row[5])  << 16);
    p0.w = (uint32)f2bf(row[6])  | ((uint32)f2bf(row[7])  << 16);
    p1.x = (uint32)f2bf(row[8])  | ((uint32)f2bf(row[9])  << 16);
    p1.y = (uint32)f2bf(row[10]) | ((uint32)f2bf(row[11]) << 16);
    p1.z = (uint32)f2bf(row[12]) | ((uint32)f2bf(row[13]) << 16);
    p1.w = (uint32)f2bf(row[14]) | ((uint32)f2bf(row[15]) << 16);
    *(uint4*)(Dt + (size_t)nd * 2048 + k0 + kc) = p0;
    *(uint4*)(Dt + (size_t)nd * 2048 + k0 + kc + 8) = p1;
}

// ---------------------------------------------------------------------------
// Fused QKV GEMM, 256x256 tile, 8-wave, template-exact 8-phase counted-vmcnt
// pipeline (r3, best measured 72.5us): 8 SEPARATE LDS half-buffers, phase =
// {ds_read frags -> stage issue -> s_barrier -> lgkmcnt(0) -> setprio MFMA ->
// s_barrier}; ONE vmcnt(6) per K-tile at end of P4 BEFORE its trailing
// barrier (3 half-tiles = 6 loads stay in flight; never 0 in main loop).
// Stage slots: P1: B[q]h1(t+1)  P2: A[p]h0(t+2)  P3: -  P4: A[p]h1+B[p]h0(t+2)
#define SB()    __builtin_amdgcn_s_barrier()
#define LGKM0() asm volatile("s_waitcnt lgkmcnt(0)" ::: "memory")
#define VM6()   asm volatile("s_waitcnt vmcnt(6)" ::: "memory")

__device__ __forceinline__ void rdA(short8 af[8], const ushort_t* Ah, int rbase, int quad)
{
    #pragma unroll
    for (int m = 0; m < 4; ++m) {
        int r = rbase + m * 16;
        #pragma unroll
        for (int ks = 0; ks < 2; ++ks)
            af[m * 2 + ks] = *(const short8*)(Ah + r * 64 + ((ks * 4 + quad) ^ (r & 7)) * 8);
    }
}
__device__ __forceinline__ void rdB(short8 bf[4], const ushort_t* Bh, int rbase, int quad)
{
    #pragma unroll
    for (int n = 0; n < 2; ++n) {
        int r = rbase + n * 32;
        #pragma unroll
        for (int ks = 0; ks < 2; ++ks)
            bf[n * 2 + ks] = *(const short8*)(Bh + r * 64 + ((ks * 4 + quad) ^ (r & 7)) * 8);
    }
}
template<int QA, int QB>
__device__ __forceinline__ void mfma16(const short8 af[8], const short8 bf[4], f32x4 acc[8][4])
{
    __builtin_amdgcn_s_setprio(1);
    #pragma unroll
    for (int m = 0; m < 4; ++m)
        #pragma unroll
        for (int n = 0; n < 2; ++n)
            #pragma unroll
            for (int ks = 0; ks < 2; ++ks)
                acc[QA * 4 + m][QB * 2 + n] = __builtin_amdgcn_mfma_f32_16x16x32_bf16(
                    af[m * 2 + ks], bf[n * 2 + ks], acc[QA * 4 + m][QB * 2 + n], 0, 0, 0);
    __builtin_amdgcn_s_setprio(0);
}

__global__ __launch_bounds__(512, 2) void gemm_qkv(
    const ushort_t* __restrict__ A, const ushort_t* __restrict__ WT,
    ushort_t* __restrict__ q1, ushort_t* __restrict__ q2,
    ushort_t* __restrict__ k1, ushort_t* __restrict__ k2,
    ushort_t* __restrict__ v1T, ushort_t* __restrict__ v2T,
    const float* __restrict__ ctab, const float* __restrict__ stab)
{
    __shared__ ushort_t sA0h0[8192], sA0h1[8192], sA1h0[8192], sA1h1[8192];
    __shared__ ushort_t sB0h0[8192], sB0h1[8192], sB1h0[8192], sB1h1[8192];
    const int tid = threadIdx.x;
    const int w = tid >> 6, lane = tid & 63;
    const int quad = lane >> 4, l15 = lane & 15;
    const int wr = w >> 2, wc = w & 3;    // 2 (M) x 4 (N) wave grid
    const int rb = blockIdx.y * 256, cbg = blockIdx.x * 256;
    const int rA = wr * 64 + l15;                         // A frag row base
    const int rB = (wc >> 1) * 64 + (wc & 1) * 16 + l15;  // B frag row base
    const int cib = w * 128;                              // per-wave chunk base

    auto stA = [&](ushort_t* buf, int ha, int tau) {
        #pragma unroll
        for (int u = 0; u < 2; ++u) {
            int ci = cib + u * 64 + lane;
            int row = ci >> 3, cc = (ci & 7) ^ (row & 7);
            gld16(buf + (cib + u * 64) * 8,
                  A + (size_t)(rb + ha * 128 + row) * 2048 + tau * 64 + cc * 8);
        }
    };
    auto stB = [&](ushort_t* buf, int hb, int tau) {
        #pragma unroll
        for (int u = 0; u < 2; ++u) {
            int ci = cib + u * 64 + lane;
            int row = ci >> 3, cc = (ci & 7) ^ (row & 7);
            gld16(buf + (cib + u * 64) * 8,
                  WT + (size_t)(cbg + hb * 128 + row) * 2048 + tau * 64 + cc * 8);
        }
    };

    // prologue: tile 0 fully + tile 1 {A h0,h1, B h0}; queue = 7 half-tiles
    stA(sA0h0, 0, 0); stA(sA0h1, 1, 0); stB(sB0h0, 0, 0); stB(sB0h1, 1, 0);
    stA(sA1h0, 0, 1); stA(sA1h1, 1, 1); stB(sB1h0, 0, 1);

    f32x4 acc[8][4];
    #pragma unroll
    for (int i = 0; i < 8; ++i)
        #pragma unroll
        for (int j = 0; j < 4; ++j) acc[i][j] = (f32x4)0.0f;
    short8 af[8], bf[4];

    VM6();                 // drain tile-0 halves (leave 3 in flight)
    SB();                  // publish across waves

    for (int it = 0; it < 16; ++it) {
        const int t = it * 2;
        const int t1 = t + 1;
        const int t2 = (t + 2 < 32) ? t + 2 : 31;
        const int t3 = (t + 3 < 32) ? t + 3 : 31;
        // ================= tile t (parity 0) =================
        rdA(af, sA0h0, rA, quad); rdB(bf, sB0h0, rB, quad);     // P1
        stB(sB1h1, 1, t1);
        SB(); LGKM0(); mfma16<0, 0>(af, bf, acc); SB();
        rdB(bf, sB0h1, rB, quad);                               // P2
        stA(sA0h0, 0, t2);
        SB(); LGKM0(); mfma16<0, 1>(af, bf, acc); SB();
        rdA(af, sA0h1, rA, quad); rdB(bf, sB0h0, rB, quad);     // P3
        SB(); LGKM0(); mfma16<1, 0>(af, bf, acc); SB();
        rdB(bf, sB0h1, rB, quad);                               // P4
        stA(sA0h1, 1, t2); stB(sB0h0, 0, t2);
        VM6();
        SB(); LGKM0(); mfma16<1, 1>(af, bf, acc); SB();
        // ================= tile t+1 (parity 1) =================
        rdA(af, sA1h0, rA, quad); rdB(bf, sB1h0, rB, quad);     // P1
        stB(sB0h1, 1, t2);
        SB(); LGKM0(); mfma16<0, 0>(af, bf, acc); SB();
        rdB(bf, sB1h1, rB, quad);                               // P2
        stA(sA1h0, 0, t3);
        SB(); LGKM0(); mfma16<0, 1>(af, bf, acc); SB();
        rdA(af, sA1h1, rA, quad); rdB(bf, sB1h0, rB, quad);     // P3
        SB(); LGKM0(); mfma16<1, 0>(af, bf, acc); SB();
        rdB(bf, sB1h1, rB, quad);                               // P4
        stA(sA1h1, 1, t3); stB(sB1h0, 0, t3);
        VM6();
        SB(); LGKM0(); mfma16<1, 1>(af, bf, acc); SB();
    }

    // per-wave output cols: col(nj) = (nj>>1)*128 + (wc>>1)*64 + (wc&1)*16 + (nj&1)*32 + l15
    // per-wave output rows: row(mi) = (mi>>2)*128 + wr*64 + (mi&3)*16 + quad*4 + r
    const int region = cbg >> 11;        // 0=Q, 1=K, 2=V
    const int nloc = cbg & 2047;
    if (region < 2) {
        ushort_t* b1 = region ? k1 : q1;
        ushort_t* b2 = region ? k2 : q2;
        const int i = (wc & 1) * 16 + l15;           // rotary index in [0,32)
        #pragma unroll
        for (int qb = 0; qb < 2; ++qb) {
            int head2 = (nloc >> 6) + qb * 2 + (wc >> 1);
            ushort_t* dst = ((head2 & 1) ? b2 : b1) + (size_t)(head2 >> 1) * 2048 * 64;
            #pragma unroll
            for (int mi = 0; mi < 8; ++mi)
                #pragma unroll
                for (int r = 0; r < 4; ++r) {
                    int t = rb + (mi >> 2) * 128 + wr * 64 + (mi & 3) * 16 + quad * 4 + r;
                    float c = ctab[t * 32 + i], s = stab[t * 32 + i];
                    float x1 = acc[mi][qb * 2 + 0][r], x2 = acc[mi][qb * 2 + 1][r];
                    dst[(size_t)t * 64 + i]      = f2bf(x1 * c - x2 * s);
                    dst[(size_t)t * 64 + 32 + i] = f2bf(x1 * s + x2 * c);
                }
        }
    } else {
        #pragma unroll
        for (int mi = 0; mi < 8; ++mi)
            #pragma unroll
            for (int nj = 0; nj < 4; ++nj) {
                int cg = nloc + (nj >> 1) * 128 + (wc >> 1) * 64 + (wc & 1) * 16
                       + (nj & 1) * 32 + l15;
                int hh = cg >> 7, pr = (cg >> 6) & 1, d = cg & 63;
                int tb = rb + (mi >> 2) * 128 + wr * 64 + (mi & 3) * 16 + quad * 4;
                ushort_t* dst = (pr ? v2T : v1T) + ((size_t)(hh * 64 + d)) * 2048 + tb;
                u64 pk = (u64)f2bf(acc[mi][nj][0])
                       | ((u64)f2bf(acc[mi][nj][1]) << 16)
                       | ((u64)f2bf(acc[mi][nj][2]) << 32)
                       | ((u64)f2bf(acc[mi][nj][3]) << 48);
                *(u64*)dst = pk;
            }
    }
}

// ---------------------------------------------------------------------------
// Pipelined merged attention, 8-wave blocks, DOUBLE-BUFFERED tiles with ONE
// barrier per step: step kt reads Tt[p], writes prefetched tile kt+1 into
// Tt[p^1] (its readers passed the previous barrier -> WAR-safe), then a single
// __syncthreads publishes. P-exchange uses a compact u64-slot layout
// (slot = u*16 + l15, 2KB/wave): writes hit banks 2*l15 (conflict-free),
// reads ds_read_b64 same (conflict-free). LDS = 64KB tiles + 16KB P = 80KB
// -> 2 blocks/CU (16 waves) preserved, barrier count per step halved.
__device__ __forceinline__ void attn_step(
    const ushort_t* __restrict__ Kb, const ushort_t* __restrict__ V1b,
    const ushort_t* __restrict__ V2b, ushort_t* __restrict__ pw,
    const short8* qb, f32x4* O, float& m_i, float& l_i,
    int quad, int l15, int row_l, bool diag)
{
    f32x4 s[4];
    #pragma unroll
    for (int j = 0; j < 4; ++j) s[j] = (f32x4)0.0f;
    #pragma unroll
    for (int ks = 0; ks < 2; ++ks)
        #pragma unroll
        for (int j = 0; j < 4; ++j) {
            int r = j * 16 + l15;
            short8 kf = *(const short8*)(Kb + r * 64 + ((ks * 4 + quad) ^ (r & 7)) * 8);
            s[j] = __builtin_amdgcn_mfma_f32_16x16x32_bf16(kf, qb[ks], s[j], 0, 0, 0);
        }
    float mx = -1e30f;
    #pragma unroll
    for (int j = 0; j < 4; ++j)
        #pragma unroll
        for (int r = 0; r < 4; ++r) {
            float v = s[j][r] * 0.125f;
            if (diag) {
                int kp = j * 16 + quad * 4 + r;
                v = (kp <= row_l) ? v : -1e30f;
            }
            s[j][r] = v;
            mx = fmaxf(mx, v);
        }
    mx = fmaxf(mx, __shfl_xor(mx, 16));
    mx = fmaxf(mx, __shfl_xor(mx, 32));
    float newm = fmaxf(m_i, mx);
    float alpha = __expf(m_i - newm);
    float sum = 0.0f;
    #pragma unroll
    for (int j = 0; j < 4; ++j) {
        float p0 = __expf(s[j][0] - newm);
        float p1 = __expf(s[j][1] - newm);
        float p2 = __expf(s[j][2] - newm);
        float p3 = __expf(s[j][3] - newm);
        sum += (p0 + p1) + (p2 + p3);
        u64 pk = (u64)f2bf(p0) | ((u64)f2bf(p1) << 16)
               | ((u64)f2bf(p2) << 32) | ((u64)f2bf(p3) << 48);
        // element (row l15, col 16j+4quad+i) -> u64 slot u = 4j+quad at u*64 + l15*4
        *(u64*)(pw + (j * 4 + quad) * 64 + l15 * 4) = pk;
    }
    sum += __shfl_xor(sum, 16);
    sum += __shfl_xor(sum, 32);
    l_i = l_i * alpha + sum;
    m_i = newm;
    float av0 = __shfl(alpha, quad * 4 + 0);
    float av1 = __shfl(alpha, quad * 4 + 1);
    float av2 = __shfl(alpha, quad * 4 + 2);
    float av3 = __shfl(alpha, quad * 4 + 3);
    #pragma unroll
    for (int nt = 0; nt < 8; ++nt) {
        O[nt][0] *= av0; O[nt][1] *= av1; O[nt][2] *= av2; O[nt][3] *= av3;
    }
    #pragma unroll
    for (int ks = 0; ks < 2; ++ks) {
        // row l15, cols k = ks*32+quad*8 .. +7  -> u64 slots u = 8ks+2quad, +1
        union { u64 q[2]; short8 v; } pu;
        pu.q[0] = *(const u64*)(pw + (8 * ks + 2 * quad + 0) * 64 + l15 * 4);
        pu.q[1] = *(const u64*)(pw + (8 * ks + 2 * quad + 1) * 64 + l15 * 4);
        short8 pf = pu.v;
        #pragma unroll
        for (int nt = 0; nt < 8; ++nt) {
            const ushort_t* Vs = (nt < 4) ? V1b : V2b;
            int d = (nt & 3) * 16 + l15;
            short8 vf = *(const short8*)(Vs + d * 64 + ((ks * 4 + quad) ^ (d & 7)) * 8);
            O[nt] = __builtin_amdgcn_mfma_f32_16x16x32_bf16(pf, vf, O[nt], 0, 0, 0);
        }
    }
}

__global__ __launch_bounds__(512, 4) void attn_pipe(
    const ushort_t* __restrict__ q1, const ushort_t* __restrict__ k1,
    const ushort_t* __restrict__ q2, const ushort_t* __restrict__ k2,
    const ushort_t* __restrict__ v1T, const ushort_t* __restrict__ v2T,
    float* __restrict__ X, const float* __restrict__ lam_ptr)
{
    __shared__ ushort_t Tt[2][4][4096];  // [parity][K1,K2,V1,V2][tile]
    __shared__ ushort_t Ps[8][1024];     // per-wave u64-slot P buffer (2KB)

    const int tid = threadIdx.x;
    const int w = tid >> 6, lane = tid & 63;
    const int quad = lane >> 4, l15 = lane & 15;
    const int pair = w >> 2, wl = w & 3;  // pair: 0=attn1 waves, 1=attn2 waves
    const int b = blockIdx.x;
    const int h = b & 15;                // head -> fixed XCD (b%8): L2 locality
    const int x16 = (b & 255) >> 4;
    const int qt = (b < 256) ? (31 - x16) : x16;  // (b,b+256) work sums to 33
    const float lam = lam_ptr[0];
    const int row_l = wl * 16 + l15;

    const ushort_t* k1h = k1 + (size_t)h * 2048 * 64;
    const ushort_t* k2h = k2 + (size_t)h * 2048 * 64;
    const ushort_t* v1h = v1T + (size_t)h * 64 * 2048;
    const ushort_t* v2h = v2T + (size_t)h * 64 * 2048;

    // Q fragments direct from global (pair selects q1/q2)
    short8 qb[2];
    {
        const ushort_t* qp = (pair ? q2 : q1)
            + ((size_t)h * 2048 + qt * 64 + wl * 16 + l15) * 64 + quad * 8;
        qb[0] = *(const short8*)(qp);
        qb[1] = *(const short8*)(qp + 32);
    }

    const int ci = tid;
    const int srow = ci >> 3, scc = (ci & 7) ^ (srow & 7);
    const int koff = srow * 64 + scc * 8;     // K tile: row stride 64
    const int voff = srow * 2048 + scc * 8;   // V^T: row stride 2048

    short8 sK1, sK2, sV1, sV2;

    sK1 = *(const short8*)(k1h + koff);
    sK2 = *(const short8*)(k2h + koff);
    sV1 = *(const short8*)(v1h + voff);
    sV2 = *(const short8*)(v2h + voff);
    *(short8*)(&Tt[0][0][ci * 8]) = sK1;
    *(short8*)(&Tt[0][1][ci * 8]) = sK2;
    *(short8*)(&Tt[0][2][ci * 8]) = sV1;
    *(short8*)(&Tt[0][3][ci * 8]) = sV2;
    __syncthreads();

    f32x4 O[8];
    #pragma unroll
    for (int i = 0; i < 8; ++i) O[i] = (f32x4)0.0f;
    float m_i = -1e30f, l_i = 0.0f;

    for (int kt = 0; kt <= qt; ++kt) {
        const int p = kt & 1;
        if (kt < qt) {
            int kb = (kt + 1) * 4096, vb = (kt + 1) * 64;
            sK1 = *(const short8*)(k1h + kb + koff);
            sK2 = *(const short8*)(k2h + kb + koff);
            sV1 = *(const short8*)(v1h + vb + voff);
            sV2 = *(const short8*)(v2h + vb + voff);
        }
        attn_step(&Tt[p][pair][0], &Tt[p][2][0], &Tt[p][3][0], &Ps[w][0],
                  qb, O, m_i, l_i, quad, l15, row_l, kt == qt);
        if (kt < qt) {
            // write tile kt+1 into the buffer whose readers passed the
            // previous barrier (WAR-safe); publish with the single barrier.
            *(short8*)(&Tt[p ^ 1][0][ci * 8]) = sK1;
            *(short8*)(&Tt[p ^ 1][1][ci * 8]) = sK2;
            *(short8*)(&Tt[p ^ 1][2][ci * 8]) = sV1;
            *(short8*)(&Tt[p ^ 1][3][ci * 8]) = sV2;
        }
        __syncthreads();
    }

    // epilogue: X = O1/l1 - lam * O2/l2; combine across pair halves via LDS.
    float sc = pair ? lam : 1.0f;
    float rr0 = sc / __shfl(l_i, quad * 4 + 0);
    float rr1 = sc / __shfl(l_i, quad * 4 + 1);
    float rr2 = sc / __shfl(l_i, quad * 4 + 2);
    float rr3 = sc / __shfl(l_i, quad * 4 + 3);

    float* LX = (float*)&Tt[0][0][0];    // 64 rows x 128 cols fp32 = 32 KB
    const int rbase = wl * 16 + quad * 4;
    if (pair) {
        #pragma unroll
        for (int nt = 0; nt < 8; ++nt) {
            int cb = nt * 16 + l15;
            LX[(rbase + 0) * 128 + cb] = O[nt][0] * rr0;
            LX[(rbase + 1) * 128 + cb] = O[nt][1] * rr1;
            LX[(rbase + 2) * 128 + cb] = O[nt][2] * rr2;
            LX[(rbase + 3) * 128 + cb] = O[nt][3] * rr3;
        }
    }
    __syncthreads();
    if (!pair) {
        int tb = qt * 64 + rbase;
        #pragma unroll
        for (int nt = 0; nt < 8; ++nt) {
            int cb = nt * 16 + l15;
            int col = h * 128 + cb;
            X[(size_t)(tb + 0) * 2048 + col] = O[nt][0] * rr0 - LX[(rbase + 0) * 128 + cb];
            X[(size_t)(tb + 1) * 2048 + col] = O[nt][1] * rr1 - LX[(rbase + 1) * 128 + cb];
            X[(size_t)(tb + 2) * 2048 + col] = O[nt][2] * rr2 - LX[(rbase + 2) * 128 + cb];
            X[(size_t)(tb + 3) * 2048 + col] = O[nt][3] * rr3 - LX[(rbase + 3) * 128 + cb];
        }
    }
}

// ---------------------------------------------------------------------------
// LDS-tiled truncated circular conv along t (129 taps); g[j]=g(tau=j-64)
__global__ __launch_bounds__(256) void conv_t(
    const float* __restrict__ X, const float* __restrict__ g, float* __restrict__ Y)
{
    __shared__ float Xs[192 * 64];
    __shared__ float gs[129];
    const int tid = threadIdx.x;
    const int c0 = blockIdx.x * 64, t0 = blockIdx.y * 64;
    const int c = tid & 63, tg = tid >> 6;
    for (int j = tg; j < 192; j += 4)
        Xs[j * 64 + c] = X[(size_t)((t0 - 64 + j) & 2047) * 2048 + c0 + c];
    if (tid < 129) gs[tid] = g[tid];
    __syncthreads();
    float accv[16];
    #pragma unroll
    for (int i = 0; i < 16; ++i) accv[i] = 0.0f;
    const int tl0 = tg * 16;
    for (int tap = 0; tap < 129; ++tap) {
        float gv = gs[tap];
        int base = (tl0 + 128 - tap) * 64 + c;
        #pragma unroll
        for (int i = 0; i < 16; ++i) accv[i] += gv * Xs[base + i * 64];
    }
    #pragma unroll
    for (int i = 0; i < 16; ++i)
        Y[(size_t)(t0 + tl0 + i) * 2048 + c0 + c] = accv[i];
}

// RMSNorm over 128 per (t,h); writes bf16 for the final GEMM
__global__ __launch_bounds__(64) void rms_bf(
    const float* __restrict__ Y, const float* __restrict__ wgt, ushort_t* __restrict__ yb)
{
    int grp = blockIdx.x;
    int t = grp >> 4, hh = grp & 15, l = threadIdx.x;
    size_t base = (size_t)t * 2048 + hh * 128;
    float a = Y[base + l];
    float b = Y[base + 64 + l];
    float ss = a * a + b * b;
    for (int off = 32; off; off >>= 1) ss += __shfl_down(ss, off);
    ss = __shfl(ss, 0);
    float r = rsqrtf(ss * (1.0f / 128.0f) + 1e-5f) * ONE_MINUS_LI;
    yb[base + l]      = f2bf(a * r * wgt[l]);
    yb[base + 64 + l] = f2bf(b * r * wgt[64 + l]);
}

// ---------------------------------------------------------------------------
// Final GEMM: 64x128 tile (grid 512 -> 2 blocks/CU). out = ybf * WoutT^T, fp32 out.
__global__ __launch_bounds__(256) void gemm_out(
    const ushort_t* __restrict__ A, const ushort_t* __restrict__ BT,
    float* __restrict__ C)
{
    __shared__ ushort_t As[4096];
    __shared__ ushort_t Bs[8192];
    const int tid = threadIdx.x;
    const int w = tid >> 6, lane = tid & 63;
    const int quad = lane >> 4, l15 = lane & 15;
    const int wr = w >> 1, wc = w & 1;
    const int rb = blockIdx.y * 64, cb = blockIdx.x * 128;

    f32x4 acc[2][4];
    #pragma unroll
    for (int i = 0; i < 2; ++i)
        #pragma unroll
        for (int j = 0; j < 4; ++j) acc[i][j] = (f32x4)0.0f;

    for (int k0 = 0; k0 < 2048; k0 += 64) {
        #pragma unroll
        for (int u = 0; u < 2; ++u) {
            int off = (w * 2 + u) * 512;
            int Lc = (off >> 3) + lane;
            int row = Lc >> 3, cc = (Lc & 7) ^ (row & 7);
            gld16(As + off, A + (size_t)(rb + row) * 2048 + k0 + cc * 8);
        }
        #pragma unroll
        for (int u = 0; u < 4; ++u) {
            int off = (w * 4 + u) * 512;
            int Lc = (off >> 3) + lane;
            int row = Lc >> 3, cc = (Lc & 7) ^ (row & 7);
            gld16(Bs + off, BT + (size_t)(cb + row) * 2048 + k0 + cc * 8);
        }
        __syncthreads();
        #pragma unroll
        for (int ks = 0; ks < 2; ++ks) {
            short8 af[2], bfr[4];
            #pragma unroll
            for (int mi = 0; mi < 2; ++mi) {
                int r = wr * 32 + mi * 16 + l15;
                af[mi] = *(const short8*)(As + r * 64 + ((ks * 4 + quad) ^ (r & 7)) * 8);
            }
            #pragma unroll
            for (int nj = 0; nj < 4; ++nj) {
                int r = wc * 64 + nj * 16 + l15;
                bfr[nj] = *(const short8*)(Bs + r * 64 + ((ks * 4 + quad) ^ (r & 7)) * 8);
            }
            #pragma unroll
            for (int mi = 0; mi < 2; ++mi)
                #pragma unroll
                for (int nj = 0; nj < 4; ++nj)
                    acc[mi][nj] = __builtin_amdgcn_mfma_f32_16x16x32_bf16(
                        af[mi], bfr[nj], acc[mi][nj], 0, 0, 0);
        }
        __syncthreads();
    }

    #pragma unroll
    for (int mi = 0; mi < 2; ++mi)
        #pragma unroll
        for (int nj = 0; nj < 4; ++nj) {
            int cg = cb + wc * 64 + nj * 16 + l15;
            #pragma unroll
            for (int r = 0; r < 4; ++r) {
                int t = rb + wr * 32 + mi * 16 + quad * 4 + r;
                C[(size_t)t * 2048 + cg] = acc[mi][nj][r];
            }
        }
}

// ---------------------------------------------------------------------------
extern "C" void kernel_launch(void* const* d_in, const int* in_sizes, int n_in,
                              void* d_out, int out_size, void* d_ws, size_t ws_size,
                              hipStream_t stream)
{
    const float* query = (const float*)d_in[0];
    const float* Wq    = (const float*)d_in[1];
    const float* Wk    = (const float*)d_in[2];
    const float* Wv    = (const float*)d_in[3];
    const float* Wout  = (const float*)d_in[4];
    const float* lq1   = (const float*)d_in[5];
    const float* lk1   = (const float*)d_in[6];
    const float* lq2   = (const float*)d_in[7];
    const float* lk2   = (const float*)d_in[8];
    const float* rmsw  = (const float*)d_in[9];
    float* out = (float*)d_out;

    const size_t MB = 1ull << 20;
    char* W = (char*)d_ws;
    ushort_t* WqT   = (ushort_t*)(W + 0 * MB);   // WqT/WkT/WvT contiguous: 24MB block
    ushort_t* WkT   = (ushort_t*)(W + 8 * MB);
    ushort_t* WvT   = (ushort_t*)(W + 16 * MB);
    ushort_t* WoutT = (ushort_t*)(W + 24 * MB);
    ushort_t* qb    = (ushort_t*)(W + 32 * MB);
    ushort_t* q1    = (ushort_t*)(W + 40 * MB);
    ushort_t* q2    = (ushort_t*)(W + 44 * MB);
    ushort_t* k1    = (ushort_t*)(W + 48 * MB);
    ushort_t* k2    = (ushort_t*)(W + 52 * MB);
    ushort_t* v1T   = (ushort_t*)(W + 56 * MB);
    ushort_t* v2T   = (ushort_t*)(W + 60 * MB);
    float*    X     = (float*)   (W + 64 * MB);
    float*    Y     = (float*)   (W + 32 * MB);  // aliases qb/q1/q2 (dead by conv time)
    ushort_t* ybf   = (ushort_t*)(W + 48 * MB);  // aliases k1/k2 (dead by rms time)
    float*    ctab  = (float*)   (W + 80 * MB);
    float*    stab  = (float*)   (W + 80 * MB + 256 * 1024);
    float*    gbuf  = (float*)   (W + 80 * MB + 512 * 1024);
    float*    lam   = (float*)   (W + 80 * MB + 520 * 1024);

    lambda_kernel<<<1, 64, 0, stream>>>(lq1, lk1, lq2, lk2, lam);
    gfilt_kernel<<<129, 256, 0, stream>>>(gbuf);
    rottab<<<256, 256, 0, stream>>>(ctab, stab);
    cvt_bf16<<<2048, 256, 0, stream>>>(query, qb);
    wtrans<<<dim3(32, 32, 4), 256, 0, stream>>>(Wq, Wk, Wv, Wout, WqT, WkT, WvT, WoutT);

    gemm_qkv<<<dim3(24, 8), 512, 0, stream>>>(qb, WqT, q1, q2, k1, k2, v1T, v2T, ctab, stab);

    attn_pipe<<<512, 512, 0, stream>>>(q1, k1, q2, k2, v1T, v2T, X, lam);

    conv_t<<<dim3(32, 32), 256, 0, stream>>>(X, gbuf, Y);
    rms_bf<<<32768, 64, 0, stream>>>(Y, rmsw, ybf);

    gemm_out<<<dim3(16, 32), 256, 0, stream>>>(ybf, WoutT, out);
}